// Round 13
// baseline (2155.470 us; speedup 1.0000x reference)
//
#include <hip/hip_runtime.h>

#define BATCH 2
#define NH    16
#define SEQ   2048
#define DH    64
#define KT    32
#define KHALF (SEQ / 2)
#define NKT2  (KHALF / KT)   // 32 tiles per k-half wave

typedef __attribute__((ext_vector_type(8))) short          bf16x8;
typedef __attribute__((ext_vector_type(4))) float          f32x4;
typedef __attribute__((ext_vector_type(4))) unsigned int   u32x4;
typedef __attribute__((ext_vector_type(4))) int            i32x4;

__device__ __forceinline__ unsigned short f2bf(float f) {   // RNE
    union { float f; unsigned int i; } c;
    c.f = f;
    unsigned int x = c.i;
    x += 0x7fffu + ((x >> 16) & 1u);
    return (unsigned short)(x >> 16);
}
__device__ __forceinline__ unsigned int pkt(float lo, float hi) {
    union { float f; unsigned int u; } a, b;
    a.f = lo; b.f = hi;
    return (b.u & 0xFFFF0000u) | (a.u >> 16);
}

template<bool ISBYTE> struct RawT {
    f32x4 k[2][4];
    f32x4 bias[2];
    unsigned int m8[2];
    i32x4 mi[2];
};

// block swizzle shared by all score-side kernels (4096 blocks)
__device__ __forceinline__ void score_coords(int bid, int wid, int l15,
                                             int& b, int& h, int& bh, int& qrow, int& k0) {
    const int orig = (bid & 7) * 512 + (bid >> 3);
    h = orig >> 8;
    const int rem = orig & 255;
    const int qt = rem >> 1;
    b = rem & 1;
    bh = b * NH + h;
    qrow = qt * 16 + l15;
    k0 = wid * KHALF;
}

// ================= score implementation (MODE 0: real exp; MODE 1: no-exp ablation) ==========
template<bool ISBYTE, int MODE>
__device__ __forceinline__ void score_impl(const float* __restrict__ qp,
                                           const float* __restrict__ kp,
                                           const void*  __restrict__ mp,
                                           const float* __restrict__ bp,
                                           float* __restrict__ attnp,
                                           float* __restrict__ lsump)
{
    const int tid  = threadIdx.x;
    const int wid  = tid >> 6;
    const int lane = tid & 63;
    const int l15  = lane & 15;
    const int g    = lane >> 4;

    const unsigned int* mw = (const unsigned int*)mp;
    if ((__any((int)(mw[lane & 31] > 1u)) != 0) != ISBYTE) return;

    int b, h, bh, qrow, k0;
    score_coords(blockIdx.x, wid, l15, b, h, bh, qrow, k0);

    const float* kbh = kp + (size_t)bh * SEQ * DH;
    const float* biasRow = bp + ((size_t)h * SEQ + qrow) * SEQ;
    const unsigned char* maskRowB = (const unsigned char*)mp + ((size_t)b * SEQ + qrow) * SEQ;
    const int*           maskRowI = (const int*)mp + ((size_t)b * SEQ + qrow) * SEQ;
    float* attnRow = attnp + ((size_t)bh * SEQ + qrow) * SEQ;

    bf16x8 qf0, qf1;
    {
        const float* qbase = qp + ((size_t)bh * SEQ + qrow) * DH + g * 8;
        #pragma unroll
        for (int j = 0; j < 8; ++j) {
            qf0[j] = (short)f2bf(qbase[j]      * 0.125f);
            qf1[j] = (short)f2bf(qbase[32 + j] * 0.125f);
        }
    }

    auto load_raw = [&](int kb, RawT<ISBYTE>& R) {
        #pragma unroll
        for (int mb = 0; mb < 2; ++mb) {
            const float* arow = kbh + (size_t)(kb + 16 * mb + l15) * DH + g * 8;
            R.k[mb][0] = *(const f32x4*)(arow);
            R.k[mb][1] = *(const f32x4*)(arow + 4);
            R.k[mb][2] = *(const f32x4*)(arow + 32);
            R.k[mb][3] = *(const f32x4*)(arow + 36);
            const int kloc = kb + 16 * mb + 4 * g;
            R.bias[mb] = *(const f32x4*)(biasRow + kloc);
            if constexpr (ISBYTE) R.m8[mb] = *(const unsigned int*)(maskRowB + kloc);
            else                  R.mi[mb] = *(const i32x4*)(maskRowI + kloc);
        }
    };

    float lsum = 0.0f;

    auto body = [&](const RawT<ISBYTE>& R, int kb) {
        #pragma unroll
        for (int mb = 0; mb < 2; ++mb) {
            union { bf16x8 v; unsigned int u[4]; } A0, A1;
            A0.u[0] = pkt(R.k[mb][0][0], R.k[mb][0][1]);
            A0.u[1] = pkt(R.k[mb][0][2], R.k[mb][0][3]);
            A0.u[2] = pkt(R.k[mb][1][0], R.k[mb][1][1]);
            A0.u[3] = pkt(R.k[mb][1][2], R.k[mb][1][3]);
            A1.u[0] = pkt(R.k[mb][2][0], R.k[mb][2][1]);
            A1.u[1] = pkt(R.k[mb][2][2], R.k[mb][2][3]);
            A1.u[2] = pkt(R.k[mb][3][0], R.k[mb][3][1]);
            A1.u[3] = pkt(R.k[mb][3][2], R.k[mb][3][3]);
            f32x4 c = (f32x4){0.f, 0.f, 0.f, 0.f};
            __builtin_amdgcn_s_setprio(1);
            c = __builtin_amdgcn_mfma_f32_16x16x32_bf16(A0.v, qf0, c, 0, 0, 0);
            c = __builtin_amdgcn_mfma_f32_16x16x32_bf16(A1.v, qf1, c, 0, 0, 0);
            __builtin_amdgcn_s_setprio(0);
            f32x4 pa;
            #pragma unroll
            for (int j = 0; j < 4; ++j) {
                const float s = c[j] + R.bias[mb][j];
                float e;
                if constexpr (MODE == 0) e = __expf(s);
                else                     e = s * 1.1f;           // ablation: no trans op
                int m;
                if constexpr (ISBYTE) m = (int)((R.m8[mb] >> (8 * j)) & 0xFFu);
                else                  m = R.mi[mb][j];
                pa[j] = m ? 0.0f : e;
            }
            lsum += pa[0] + pa[1] + pa[2] + pa[3];
            *(f32x4*)(attnRow + kb + 16 * mb + 4 * g) = pa;
        }
    };

    {
        RawT<ISBYTE> RA, RB;
        load_raw(k0, RA);
        load_raw(k0 + KT, RB);
        for (int kt = 0; kt < NKT2; kt += 2) {
            const int kb2 = k0 + (((kt + 2) & (NKT2 - 1)) * KT);
            const int kb3 = k0 + (((kt + 3) & (NKT2 - 1)) * KT);
            body(RA, k0 + kt * KT);
            load_raw(kb2, RA);
            body(RB, k0 + kt * KT + KT);
            load_raw(kb3, RB);
        }
    }

    lsum += __shfl_xor(lsum, 16, 64);
    lsum += __shfl_xor(lsum, 32, 64);
    if (g == 0) atomicAdd(&lsump[(size_t)bh * SEQ + qrow], lsum);
}

// A-reference: plain LB(128) — reproduces round 12 (expect VGPR ~68, sunk pipeline)
template<bool ISBYTE>
__global__ __launch_bounds__(128)
void sdpa_scoreA(const float* qp, const float* kp, const void* mp, const float* bp,
                 float* attnp, float* lsump)
{ score_impl<ISBYTE, 0>(qp, kp, mp, bp, attnp, lsump); }

// A2 / real: LB(128,2) — 256-VGPR budget so both prefetch slots stay register-resident
template<bool ISBYTE>
__global__ __launch_bounds__(128, 2)
void sdpa_score2(const float* qp, const float* kp, const void* mp, const float* bp,
                 float* attnp, float* lsump)
{ score_impl<ISBYTE, 0>(qp, kp, mp, bp, attnp, lsump); }

// ablation: no exp (everything else identical to A)
template<bool ISBYTE>
__global__ __launch_bounds__(128)
void abl_noexp(const float* qp, const float* kp, const void* mp, const float* bp,
               float* attnp, float* lsump)
{ score_impl<ISBYTE, 1>(qp, kp, mp, bp, attnp, lsump); }

// ablation: K+bias load stream only (D=2 ring, asm-sunk, no MFMA/exp/store)
__global__ __launch_bounds__(128)
void abl_loads(const float* __restrict__ kp, const float* __restrict__ bp)
{
    const int tid  = threadIdx.x;
    const int wid  = tid >> 6;
    const int lane = tid & 63;
    const int l15  = lane & 15;
    const int g    = lane >> 4;
    int b, h, bh, qrow, k0;
    score_coords(blockIdx.x, wid, l15, b, h, bh, qrow, k0);

    const float* kbh = kp + (size_t)bh * SEQ * DH;
    const float* biasRow = bp + ((size_t)h * SEQ + qrow) * SEQ;

    struct KB { f32x4 k[2][4]; f32x4 bias[2]; };
    auto load_raw = [&](int kb, KB& R) {
        #pragma unroll
        for (int mb = 0; mb < 2; ++mb) {
            const float* arow = kbh + (size_t)(kb + 16 * mb + l15) * DH + g * 8;
            R.k[mb][0] = *(const f32x4*)(arow);
            R.k[mb][1] = *(const f32x4*)(arow + 4);
            R.k[mb][2] = *(const f32x4*)(arow + 32);
            R.k[mb][3] = *(const f32x4*)(arow + 36);
            R.bias[mb] = *(const f32x4*)(biasRow + kb + 16 * mb + 4 * g);
        }
    };
    f32x4 acc = (f32x4){0.f, 0.f, 0.f, 0.f};
    auto body = [&](const KB& R) {
        #pragma unroll
        for (int mb = 0; mb < 2; ++mb) {
            #pragma unroll
            for (int i = 0; i < 4; ++i) acc += R.k[mb][i];
            acc += R.bias[mb];
        }
    };
    {
        KB RA, RB;
        load_raw(k0, RA);
        load_raw(k0 + KT, RB);
        for (int kt = 0; kt < NKT2; kt += 2) {
            const int kb2 = k0 + (((kt + 2) & (NKT2 - 1)) * KT);
            const int kb3 = k0 + (((kt + 3) & (NKT2 - 1)) * KT);
            body(RA);  load_raw(kb2, RA);
            body(RB);  load_raw(kb3, RB);
        }
    }
    asm volatile("" :: "v"(acc[0]), "v"(acc[1]), "v"(acc[2]), "v"(acc[3]));  // keep live, no store
}

// ablation: attn-pattern stores only (no loads beyond one q vector)
__global__ __launch_bounds__(128)
void abl_store(const float* __restrict__ qp, float* __restrict__ attnp)
{
    const int tid  = threadIdx.x;
    const int wid  = tid >> 6;
    const int lane = tid & 63;
    const int l15  = lane & 15;
    const int g    = lane >> 4;
    int b, h, bh, qrow, k0;
    score_coords(blockIdx.x, wid, l15, b, h, bh, qrow, k0);

    float* attnRow = attnp + ((size_t)bh * SEQ + qrow) * SEQ;
    const float* qbase = qp + ((size_t)bh * SEQ + qrow) * DH + g * 8;
    f32x4 s0 = *(const f32x4*)qbase;
    f32x4 s1 = *(const f32x4*)(qbase + 4);

    for (int kt = 0; kt < NKT2; ++kt) {
        const int kb = k0 + kt * KT;
        *(f32x4*)(attnRow + kb + 4 * g)      = s0;
        *(f32x4*)(attnRow + kb + 16 + 4 * g) = s1;
    }
}

// ========== pv (round-12 body, LB(128,2)) ==========
__global__ __launch_bounds__(128, 2)
void sdpa_pv2(const float* __restrict__ vp,
              float* __restrict__ attnp,
              const float* __restrict__ lsump,
              float* __restrict__ outp)
{
    __shared__ __align__(16) unsigned short P_lds[2][16 * 40];
    __shared__ float OA[16][65];

    const int tid  = threadIdx.x;
    const int wid  = tid >> 6;
    const int lane = tid & 63;
    const int l15  = lane & 15;
    const int g    = lane >> 4;
    const int r    = lane >> 2;
    const int c0   = (lane & 3) * 8;

    const int bid  = blockIdx.x;
    const int orig = (bid & 7) * 512 + (bid >> 3);
    const int bh   = orig >> 7;
    const int qt   = orig & 127;
    const int k0   = wid * KHALF;

    float* rowPtr   = attnp + ((size_t)bh * SEQ + qt * 16 + r) * SEQ + k0;
    const float rv  = 1.0f / lsump[(size_t)bh * SEQ + qt * 16 + r];
    const float* vbh = vp + (size_t)bh * SEQ * DH + (size_t)k0 * DH;
    unsigned short* plw = &P_lds[wid][0];

    f32x4 accO[4];
    #pragma unroll
    for (int i = 0; i < 4; ++i) accO[i] = (f32x4){0.f, 0.f, 0.f, 0.f};

    struct Slot { f32x4 a0, a1; float v[4][8]; };

    auto load_slot = [&](int kc, Slot& S) {
        const float* ap = rowPtr + kc * KT + c0;
        S.a0 = *(const f32x4*)ap;
        S.a1 = *(const f32x4*)(ap + 4);
        const float* vb2 = vbh + (size_t)kc * KT * DH + 512 * g + l15;
        #pragma unroll
        for (int nb = 0; nb < 4; ++nb)
            #pragma unroll
            for (int j = 0; j < 8; ++j)
                S.v[nb][j] = vb2[j * 64 + 16 * nb];
    };

    auto body = [&](const Slot& S, int kc) {
        f32x4 s0, s1;
        #pragma unroll
        for (int j = 0; j < 4; ++j) { s0[j] = S.a0[j] * rv; s1[j] = S.a1[j] * rv; }
        float* ap = rowPtr + kc * KT + c0;
        *(f32x4*)ap       = s0;
        *(f32x4*)(ap + 4) = s1;
        u32x4 w;
        w[0] = pkt(s0[0], s0[1]);  w[1] = pkt(s0[2], s0[3]);
        w[2] = pkt(s1[0], s1[1]);  w[3] = pkt(s1[2], s1[3]);
        *(u32x4*)(plw + r * 40 + c0) = w;
        union { bf16x8 v; unsigned int u[4]; } vf[4];
        #pragma unroll
        for (int nb = 0; nb < 4; ++nb)
            #pragma unroll
            for (int i = 0; i < 4; ++i)
                vf[nb].u[i] = pkt(S.v[nb][2 * i], S.v[nb][2 * i + 1]);
        bf16x8 pf = *(const bf16x8*)(plw + l15 * 40 + g * 8);
        __builtin_amdgcn_s_setprio(1);
        #pragma unroll
        for (int nb = 0; nb < 4; ++nb)
            accO[nb] = __builtin_amdgcn_mfma_f32_16x16x32_bf16(pf, vf[nb].v, accO[nb], 0, 0, 0);
        __builtin_amdgcn_s_setprio(0);
    };

    {
        Slot SA, SB;
        load_slot(0, SA);
        load_slot(1, SB);
        for (int kc = 0; kc < NKT2; kc += 2) {
            const int k2 = (kc + 2) & (NKT2 - 1);
            const int k3 = (kc + 3) & (NKT2 - 1);
            body(SA, kc);
            load_slot(k2, SA);
            body(SB, kc + 1);
            load_slot(k3, SB);
        }
    }

    if (wid == 1) {
        #pragma unroll
        for (int rr = 0; rr < 4; ++rr)
            #pragma unroll
            for (int nb = 0; nb < 4; ++nb)
                OA[4 * g + rr][16 * nb + l15] = accO[nb][rr];
    }
    __syncthreads();

    if (wid == 0) {
        float* outBase = outp + ((size_t)bh * SEQ + qt * 16) * DH;
        #pragma unroll
        for (int rr = 0; rr < 4; ++rr)
            #pragma unroll
            for (int nb = 0; nb < 4; ++nb)
                outBase[(4 * g + rr) * DH + 16 * nb + l15] =
                    accO[nb][rr] + OA[4 * g + rr][16 * nb + l15];
    }
}

extern "C" void kernel_launch(void* const* d_in, const int* in_sizes, int n_in,
                              void* d_out, int out_size, void* d_ws, size_t ws_size,
                              hipStream_t stream) {
    const float* qp = (const float*)d_in[0];
    const float* kp = (const float*)d_in[1];
    const float* vp = (const float*)d_in[2];
    const void*  mp = d_in[3];
    const float* bp = (const float*)d_in[4];

    float* outp  = (float*)d_out;
    float* attnp = outp + (size_t)BATCH * NH * SEQ * DH;
    float* lsump = (float*)d_ws;

    dim3 grid(4096), block(128);

    // ---- diagnostics (outputs overwritten by the real kernels below) ----
    abl_loads<<<grid, block, 0, stream>>>(kp, bp);
    abl_store<<<grid, block, 0, stream>>>(qp, attnp);
    abl_noexp<true ><<<grid, block, 0, stream>>>(qp, kp, mp, bp, attnp, lsump);
    abl_noexp<false><<<grid, block, 0, stream>>>(qp, kp, mp, bp, attnp, lsump);
    sdpa_scoreA<true ><<<grid, block, 0, stream>>>(qp, kp, mp, bp, attnp, lsump);  // 68-VGPR ref
    sdpa_scoreA<false><<<grid, block, 0, stream>>>(qp, kp, mp, bp, attnp, lsump);

    // ---- real computation ----
    hipMemsetAsync(lsump, 0, (size_t)BATCH * NH * SEQ * sizeof(float), stream);
    sdpa_score2<true ><<<grid, block, 0, stream>>>(qp, kp, mp, bp, attnp, lsump);  // LB(128,2)
    sdpa_score2<false><<<grid, block, 0, stream>>>(qp, kp, mp, bp, attnp, lsump);
    sdpa_pv2<<<grid, block, 0, stream>>>(vp, attnp, lsump, outp);
}

// Round 14
// 692.038 us; speedup vs baseline: 3.1147x; 3.1147x over previous
//
#include <hip/hip_runtime.h>

#define BATCH 2
#define NH    16
#define SEQ   2048
#define DH    64
#define KT    32
#define KHALF (SEQ / 2)
#define CH    128              // chunk columns (contiguity unit = 512B/row)
#define NCH   (KHALF / CH)     // 8 chunks per k-half
#define NSUB  (CH / KT)        // 4 MFMA sub-tiles per chunk
#define SSTR  132              // score LDS row stride in dwords (128+4 pad, 16B-aligned)
#define PSTR  136              // pv LDS row stride in bf16 elems (272B, 16B-aligned)

typedef __attribute__((ext_vector_type(8))) short          bf16x8;
typedef __attribute__((ext_vector_type(4))) float          f32x4;
typedef __attribute__((ext_vector_type(2))) unsigned int   u32x2;
typedef __attribute__((ext_vector_type(4))) int            i32x4;
typedef __attribute__((ext_vector_type(4))) unsigned char  u8x4;

__device__ __forceinline__ unsigned short f2bf(float f) {   // RNE (Q only)
    union { float f; unsigned int i; } c;
    c.f = f;
    unsigned int x = c.i;
    x += 0x7fffu + ((x >> 16) & 1u);
    return (unsigned short)(x >> 16);
}
// truncation pack: two f32 -> one u32 of 2 bf16
__device__ __forceinline__ unsigned int pkt(float lo, float hi) {
    union { float f; unsigned int u; } a, b;
    a.f = lo; b.f = hi;
    return (b.u & 0xFFFF0000u) | (a.u >> 16);
}

// ============ kernel 1: scores with LDS pivot for contiguous bias/mask/attn I/O ============
// Per wave: 16 q-rows x one k-half. Produce: K(L2)+MFMA -> raw scores into LDS chunk.
// Consume: LDS row-contiguous + bias/mask contiguous (2 rows x 512B per instr) -> exp ->
// row-sum shuffles -> attn store contiguous.
template<bool ISBYTE>
__global__ __launch_bounds__(128, 2)
void sdpa_score(const float* __restrict__ qp,
                const float* __restrict__ kp,
                const void*  __restrict__ mp,
                const float* __restrict__ bp,
                float* __restrict__ attnp,
                float* __restrict__ lsump)
{
    __shared__ __align__(16) float S_lds[2][16 * SSTR];   // raw-score chunk per wave

    const int tid  = threadIdx.x;
    const int wid  = tid >> 6;          // k-half
    const int lane = tid & 63;
    const int l15  = lane & 15;         // q (fragment layout)
    const int g    = lane >> 4;
    const int cl   = lane & 31;         // consume: col-lane (16B granule)
    const int hi   = lane >> 5;         // consume: row parity

    const unsigned int* mw = (const unsigned int*)mp;
    if ((__any((int)(mw[lane & 31] > 1u)) != 0) != ISBYTE) return;

    const int bid  = blockIdx.x;
    const int orig = (bid & 7) * 512 + (bid >> 3);   // bijective XCD swizzle
    const int h    = orig >> 8;
    const int rem  = orig & 255;
    const int qt   = rem >> 1;
    const int b    = rem & 1;                        // b-pair adjacent -> bias L2 share
    const int bh   = b * NH + h;
    const int qbase = qt * 16;
    const int k0   = wid * KHALF;

    const float* kbh = kp + (size_t)bh * SEQ * DH;
    float* sw = &S_lds[wid][0];

    // Q fragment (B-operand of swapped QK^T), prescaled by 1/8
    bf16x8 qf0, qf1;
    {
        const float* qb = qp + ((size_t)bh * SEQ + qbase + l15) * DH + g * 8;
        #pragma unroll
        for (int j = 0; j < 8; ++j) {
            qf0[j] = (short)f2bf(qb[j]      * 0.125f);
            qf1[j] = (short)f2bf(qb[32 + j] * 0.125f);
        }
    }

    struct KS { f32x4 k[2][4]; };
    auto load_k = [&](int tk, KS& R) {               // tk = sub-tile idx in k-half
        const int kb = k0 + tk * KT;
        #pragma unroll
        for (int mb = 0; mb < 2; ++mb) {
            const float* arow = kbh + (size_t)(kb + 16 * mb + l15) * DH + g * 8;
            R.k[mb][0] = *(const f32x4*)(arow);
            R.k[mb][1] = *(const f32x4*)(arow + 4);
            R.k[mb][2] = *(const f32x4*)(arow + 32);
            R.k[mb][3] = *(const f32x4*)(arow + 36);
        }
    };

    auto produce = [&](const KS& R, int ko) {        // ko = col offset in chunk
        #pragma unroll
        for (int mb = 0; mb < 2; ++mb) {
            union { bf16x8 v; unsigned int u[4]; } A0, A1;
            A0.u[0] = pkt(R.k[mb][0][0], R.k[mb][0][1]);
            A0.u[1] = pkt(R.k[mb][0][2], R.k[mb][0][3]);
            A0.u[2] = pkt(R.k[mb][1][0], R.k[mb][1][1]);
            A0.u[3] = pkt(R.k[mb][1][2], R.k[mb][1][3]);
            A1.u[0] = pkt(R.k[mb][2][0], R.k[mb][2][1]);
            A1.u[1] = pkt(R.k[mb][2][2], R.k[mb][2][3]);
            A1.u[2] = pkt(R.k[mb][3][0], R.k[mb][3][1]);
            A1.u[3] = pkt(R.k[mb][3][2], R.k[mb][3][3]);
            f32x4 c = (f32x4){0.f, 0.f, 0.f, 0.f};
            __builtin_amdgcn_s_setprio(1);
            c = __builtin_amdgcn_mfma_f32_16x16x32_bf16(A0.v, qf0, c, 0, 0, 0);
            c = __builtin_amdgcn_mfma_f32_16x16x32_bf16(A1.v, qf1, c, 0, 0, 0);
            __builtin_amdgcn_s_setprio(0);
            // raw scores -> LDS [q=l15][ko+16mb+4g .. +3]
            *(f32x4*)(sw + l15 * SSTR + ko + 16 * mb + 4 * g) = c;
        }
    };

    float rs[8];
    #pragma unroll
    for (int i = 0; i < 8; ++i) rs[i] = 0.0f;

    KS RA, RB;
    load_k(0, RA);
    load_k(1, RB);

    for (int c = 0; c < NCH; ++c) {
        const int colbase = k0 + c * CH;

        // issue bias (+mask) for this chunk, contiguous: 2 rows x 512B per instr
        f32x4 biasv[8];
        unsigned int mk8[8];
        i32x4 mk32[8];
        #pragma unroll
        for (int i = 0; i < 8; ++i) {
            const int row = qbase + 2 * i + hi;
            biasv[i] = *(const f32x4*)(bp + ((size_t)h * SEQ + row) * SEQ + colbase + 4 * cl);
            if constexpr (ISBYTE)
                mk8[i] = *(const unsigned int*)((const unsigned char*)mp +
                          ((size_t)b * SEQ + row) * SEQ + colbase + 4 * cl);
            else
                mk32[i] = *(const i32x4*)((const int*)mp +
                          ((size_t)b * SEQ + row) * SEQ + colbase + 4 * cl);
        }

        // produce 4 sub-tiles into the LDS chunk (K ring: distance-2 reissue)
        #pragma unroll
        for (int s = 0; s < NSUB; ++s) {
            const int tk = 4 * c + s;
            if ((s & 1) == 0) { produce(RA, s * KT); load_k((tk + 2) & 31, RA); }
            else              { produce(RB, s * KT); load_k((tk + 2) & 31, RB); }
        }

        // consume: LDS raw + bias -> exp -> row-sum -> attn (contiguous)
        #pragma unroll
        for (int i = 0; i < 8; ++i) {
            const int row = 2 * i + hi;
            f32x4 p = *(const f32x4*)(sw + row * SSTR + 4 * cl);
            f32x4 pa;
            #pragma unroll
            for (int j = 0; j < 4; ++j) {
                const float s = p[j] + biasv[i][j];
                int m;
                if constexpr (ISBYTE) m = (int)((mk8[i] >> (8 * j)) & 0xFFu);
                else                  m = mk32[i][j];
                pa[j] = m ? 0.0f : __expf(s);
            }
            float t = pa[0] + pa[1] + pa[2] + pa[3];
            t += __shfl_xor(t, 1, 64);
            t += __shfl_xor(t, 2, 64);
            t += __shfl_xor(t, 4, 64);
            t += __shfl_xor(t, 8, 64);
            t += __shfl_xor(t, 16, 64);
            rs[i] += t;
            *(f32x4*)(attnp + ((size_t)bh * SEQ + qbase + row) * SEQ + colbase + 4 * cl) = pa;
        }
    }

    // 2 atomic adds per row total (one per k-half) -> deterministic
    if (cl == 0) {
        #pragma unroll
        for (int i = 0; i < 8; ++i)
            atomicAdd(&lsump[(size_t)bh * SEQ + qbase + 2 * i + hi], rs[i]);
    }
}

// ============ kernel 2: normalize attn (contiguous R/W) + out = P_norm . V ============
__global__ __launch_bounds__(128, 2)
void sdpa_pv(const float* __restrict__ vp,
             float* __restrict__ attnp,
             const float* __restrict__ lsump,
             float* __restrict__ outp)
{
    __shared__ __align__(16) unsigned short P_lds[2][16 * PSTR];
    __shared__ float OA[16][65];

    const int tid  = threadIdx.x;
    const int wid  = tid >> 6;
    const int lane = tid & 63;
    const int l15  = lane & 15;
    const int g    = lane >> 4;
    const int cl   = lane & 31;
    const int hi   = lane >> 5;

    const int bid  = blockIdx.x;
    const int orig = (bid & 7) * 512 + (bid >> 3);
    const int bh   = orig >> 7;                      // 4 bh per XCD -> V fits L2
    const int qt   = orig & 127;
    const int qbase = qt * 16;
    const int k0   = wid * KHALF;

    float rv8[8];
    #pragma unroll
    for (int i = 0; i < 8; ++i)
        rv8[i] = 1.0f / lsump[(size_t)bh * SEQ + qbase + 2 * i + hi];

    const float* vbh = vp + (size_t)bh * SEQ * DH + (size_t)k0 * DH;
    unsigned short* pw = &P_lds[wid][0];

    f32x4 accO[4];   // accO[nb][rr] = O[q=qbase+4g+rr][d=16nb+l15]
    #pragma unroll
    for (int i = 0; i < 4; ++i) accO[i] = (f32x4){0.f, 0.f, 0.f, 0.f};

    struct VS { float v[4][8]; };
    auto load_v = [&](int tk, VS& S) {
        const float* vb2 = vbh + (size_t)tk * KT * DH + 512 * g + l15;
        #pragma unroll
        for (int nb = 0; nb < 4; ++nb)
            #pragma unroll
            for (int j = 0; j < 8; ++j)
                S.v[nb][j] = vb2[j * 64 + 16 * nb];
    };

    auto load_av = [&](int c, f32x4* av) {           // 2 rows x 512B per instr
        #pragma unroll
        for (int i = 0; i < 8; ++i)
            av[i] = *(const f32x4*)(attnp + ((size_t)bh * SEQ + qbase + 2 * i + hi) * SEQ
                                    + k0 + c * CH + 4 * cl);
    };
    auto consume_av = [&](int c, const f32x4* av) {  // normalize, store, pack to LDS
        #pragma unroll
        for (int i = 0; i < 8; ++i) {
            const int row = 2 * i + hi;
            f32x4 sc;
            #pragma unroll
            for (int j = 0; j < 4; ++j) sc[j] = av[i][j] * rv8[i];
            *(f32x4*)(attnp + ((size_t)bh * SEQ + qbase + row) * SEQ
                      + k0 + c * CH + 4 * cl) = sc;
            u32x2 w;
            w[0] = pkt(sc[0], sc[1]);
            w[1] = pkt(sc[2], sc[3]);
            *(u32x2*)(pw + row * PSTR + 4 * cl) = w;  // bf16 cols 4cl..4cl+3
        }
    };
    auto frag = [&](int c, VS& SA, VS& SB) {         // PV MFMAs for this chunk
        #pragma unroll
        for (int s = 0; s < NSUB; ++s) {
            const int tk = 4 * c + s;
            VS& S = (s & 1) ? SB : SA;               // static parity (tk enters even)
            union { bf16x8 v; unsigned int u[4]; } vf[4];
            #pragma unroll
            for (int nb = 0; nb < 4; ++nb)
                #pragma unroll
                for (int i = 0; i < 4; ++i)
                    vf[nb].u[i] = pkt(S.v[nb][2 * i], S.v[nb][2 * i + 1]);
            bf16x8 pf = *(const bf16x8*)(pw + l15 * PSTR + s * KT + 8 * g);
            __builtin_amdgcn_s_setprio(1);
            #pragma unroll
            for (int nb = 0; nb < 4; ++nb)
                accO[nb] = __builtin_amdgcn_mfma_f32_16x16x32_bf16(pf, vf[nb].v, accO[nb], 0, 0, 0);
            __builtin_amdgcn_s_setprio(0);
            load_v((tk + 2) & 31, S);
        }
    };

    {
        VS VA, VB;
        f32x4 avA[8], avB[8];
        load_v(0, VA);
        load_v(1, VB);
        load_av(0, avA);
        for (int c = 0; c < NCH; c += 2) {
            load_av(c + 1, avB);                     // dbuf: next chunk's attn in flight
            consume_av(c, avA);
            frag(c, VA, VB);
            if (c + 2 < NCH) load_av(c + 2, avA);
            consume_av(c + 1, avB);
            frag(c + 1, VA, VB);
        }
    }

    // cross-wave combine: wave1 deposits its k-half, wave0 adds + writes out
    if (wid == 1) {
        #pragma unroll
        for (int rr = 0; rr < 4; ++rr)
            #pragma unroll
            for (int nb = 0; nb < 4; ++nb)
                OA[4 * g + rr][16 * nb + l15] = accO[nb][rr];
    }
    __syncthreads();

    if (wid == 0) {
        float* outBase = outp + ((size_t)bh * SEQ + qbase) * DH;
        #pragma unroll
        for (int rr = 0; rr < 4; ++rr)
            #pragma unroll
            for (int nb = 0; nb < 4; ++nb)
                outBase[(4 * g + rr) * DH + 16 * nb + l15] =
                    accO[nb][rr] + OA[4 * g + rr][16 * nb + l15];
    }
}

extern "C" void kernel_launch(void* const* d_in, const int* in_sizes, int n_in,
                              void* d_out, int out_size, void* d_ws, size_t ws_size,
                              hipStream_t stream) {
    const float* qp = (const float*)d_in[0];
    const float* kp = (const float*)d_in[1];
    const float* vp = (const float*)d_in[2];
    const void*  mp = d_in[3];
    const float* bp = (const float*)d_in[4];

    float* outp  = (float*)d_out;
    float* attnp = outp + (size_t)BATCH * NH * SEQ * DH;   // out first, then attn (f32)
    float* lsump = (float*)d_ws;                            // 256 KB scratch

    hipMemsetAsync(lsump, 0, (size_t)BATCH * NH * SEQ * sizeof(float), stream);

    dim3 grid(4096), block(128);
    // mask layout resolved on-device; mismatched instantiation exits immediately
    sdpa_score<true ><<<grid, block, 0, stream>>>(qp, kp, mp, bp, attnp, lsump);
    sdpa_score<false><<<grid, block, 0, stream>>>(qp, kp, mp, bp, attnp, lsump);

    sdpa_pv<<<grid, block, 0, stream>>>(vp, attnp, lsump, outp);
}